// Round 3
// baseline (180.766 us; speedup 1.0000x reference)
//
#include <hip/hip_runtime.h>

// Problem constants (match reference)
constexpr int B = 32, N = 256, C = 3, H = 512, W = 512, K = 32;

typedef float f32x4 __attribute__((ext_vector_type(4)));

// Block = 256 threads = FOUR consecutive bn cells across all 3 channels.
// Per thread: 12 independent gather loads in flight (4 bn x 3 planes),
// 1 gaussian load, 12 coalesced stores. Grid = 2048 blocks = 8192 waves
// = exactly one full-machine cohort (256 CU x 32 waves/CU).
__global__ __launch_bounds__(256) void rgte_kernel(
    const float* __restrict__ img,
    const int*   __restrict__ mu,
    const float* __restrict__ gauss,
    float*       __restrict__ out)
{
    // XCD-chunked swizzle: 2048 blocks round-robin XCDs (bid & 7); XCD i
    // gets bn range [i*1024, (i+1)*1024) -> 3 MB image slice fits 4 MB L2.
    const int bid = blockIdx.x;
    const int xcd = bid & 7;
    const int idx = bid >> 3;              // 0..255 within XCD chunk
    const int bn0 = xcd * 1024 + idx * 4;  // 4 consecutive bn, same b
    const int b   = bn0 >> 8;              // N = 256; uniform across the 4

    const int local = threadIdx.x;
    const int kx4   = local & 7;           // 8 float4 per K-row
    const int ky    = local >> 3;          // 32 rows

    constexpr int PLANE = H * W;
    const float* plane0 = img + (b * C * H + ky) * W + kx4 * 4;

    // Block-uniform mu pairs -> scalar loads.
    int m0[4], m1[4];
#pragma unroll
    for (int i = 0; i < 4; ++i) {
        m0[i] = mu[2 * (bn0 + i)];
        m1[i] = mu[2 * (bn0 + i) + 1];
    }

    // Issue all 12 gather loads back-to-back (independent, 16B each;
    // gfx9+ global HW handles 4B-aligned dwordx4).
    f32x4 v[4][3];
#pragma unroll
    for (int i = 0; i < 4; ++i) {
        const float* row = plane0 + m0[i] * W + m1[i];
        v[i][0] = *reinterpret_cast<const f32x4*>(row);
        v[i][1] = *reinterpret_cast<const f32x4*>(row + PLANE);
        v[i][2] = *reinterpret_cast<const f32x4*>(row + 2 * PLANE);
    }

    // Gaussian chunk: 16B-aligned, L1-resident (4 KB), read once for all 12.
    f32x4 g = *reinterpret_cast<const f32x4*>(gauss + ky * K + kx4 * 4);

    // Coalesced stores: per (i,c) a wave writes one contiguous 1 KB segment.
    // out f32x4 index = bn*768 + c*256 + local
    f32x4* out4 = reinterpret_cast<f32x4*>(out) + (bn0 * (C * 256) + local);
#pragma unroll
    for (int i = 0; i < 4; ++i) {
        out4[i * 768 + 0]   = v[i][0] * g;
        out4[i * 768 + 256] = v[i][1] * g;
        out4[i * 768 + 512] = v[i][2] * g;
    }
}

extern "C" void kernel_launch(void* const* d_in, const int* in_sizes, int n_in,
                              void* d_out, int out_size, void* d_ws, size_t ws_size,
                              hipStream_t stream) {
    const float* img   = (const float*)d_in[0];
    const int*   mu    = (const int*)d_in[1];
    const float* gauss = (const float*)d_in[2];
    float*       out   = (float*)d_out;

    rgte_kernel<<<(B * N) / 4, 256, 0, stream>>>(img, mu, gauss, out);
}